// Round 13
// baseline (225.097 us; speedup 1.0000x reference)
//
#include <hip/hip_runtime.h>
#include <hip/hip_bf16.h>

// B=2, S=2048, D=1024, H=16, dk=64. fp32 in/out; bf16 MFMA compute.
#define SEQ 2048
#define DIM 1024
#define NH  16
#define DK  64
#define NA  (2 * SEQ * DIM)   // activation elems
#define NW  (DIM * DIM)       // weight elems
#define PSTR 72               // padded P row stride (bf16)
#define ESTR 136              // epilogue bf16 tile stride (16B-aligned rows)
#define FSTR 132              // epilogue fp32 tile stride (16B-aligned rows)
#define QSCALE 0.18033688011112042f  // 0.125 * log2(e)

typedef __attribute__((ext_vector_type(4))) float f32x4;
typedef __attribute__((ext_vector_type(8))) __bf16 bf16x8;
typedef __attribute__((ext_vector_type(4))) __bf16 bf16x4;

__device__ __forceinline__ f32x4 mfma16(bf16x8 a, bf16x8 b, f32x4 c) {
  return __builtin_amdgcn_mfma_f32_16x16x32_bf16(a, b, c, 0, 0, 0);
}
__device__ __forceinline__ void async_load16(const void* g, void* l) {
  __builtin_amdgcn_global_load_lds(
      (const __attribute__((address_space(1))) void*)g,
      (__attribute__((address_space(3))) void*)l, 16, 0, 0);
}
// XOR-swizzled 16B-chunk slot for a [rows x 64bf16] tile (4 chunk bits->8 grp).
__device__ __forceinline__ int swz(int row, int chunk) {
  return row * 8 + (chunk ^ (row & 7));
}
// XOR-swizzled slot for a [rows x 32bf16] tile (4 chunks/row; 16 rows -> 8
// bank-groups x 2-way = conflict-free).
__device__ __forceinline__ int swz32(int row, int chunk) {
  return row * 4 + (chunk ^ ((row >> 1) & 3));
}

// ---------------------------------------------------------------------------
// fp32 -> bf16 conversion + mask->bias precompute. grid 8193.
// ---------------------------------------------------------------------------
__global__ __launch_bounds__(256) void cvt_kernel(
    const float* __restrict__ s0, const float* __restrict__ s1,
    const float* __restrict__ s2, const float* __restrict__ s3,
    const float* __restrict__ s4, const float* __restrict__ s5,
    const float* __restrict__ s6, const int* __restrict__ mask,
    __hip_bfloat16* __restrict__ d0, __hip_bfloat16* __restrict__ d1,
    __hip_bfloat16* __restrict__ d2, __hip_bfloat16* __restrict__ d3,
    __hip_bfloat16* __restrict__ d4, __hip_bfloat16* __restrict__ d5,
    __hip_bfloat16* __restrict__ d6, float* __restrict__ biasg) {
  const int id = blockIdx.x;
  if (id == 8192) {
    for (int i = threadIdx.x; i < 2 * SEQ; i += 256)
      biasg[i] = mask[i] ? 0.f : -1e9f;
    return;
  }
  const float* s;
  __hip_bfloat16* d;
  int bid;
  if (id < 6144) {
    int t = id >> 11;
    bid = id & 2047;
    s = (t == 0) ? s0 : ((t == 1) ? s1 : s2);
    d = (t == 0) ? d0 : ((t == 1) ? d1 : d2);
  } else {
    int t = (id - 6144) >> 9;
    bid = (id - 6144) & 511;
    s = (t == 0) ? s3 : ((t == 1) ? s4 : ((t == 2) ? s5 : s6));
    d = (t == 0) ? d3 : ((t == 1) ? d4 : ((t == 2) ? d5 : d6));
  }
  size_t i = ((size_t)bid * 256 + threadIdx.x) * 8;
  float4 a = *(const float4*)(s + i);
  float4 b = *(const float4*)(s + i + 4);
  bf16x8 v = {(__bf16)a.x, (__bf16)a.y, (__bf16)a.z, (__bf16)a.w,
              (__bf16)b.x, (__bf16)b.y, (__bf16)b.z, (__bf16)b.w};
  *(bf16x8*)(d + i) = v;
}

// ---------------------------------------------------------------------------
// QKV GEMM mainloop: BK=32, double-buffered, 32 KB staging (fits in the
// 34.8 KB epilogue-tile union -> 3 blocks/CU, 768-block grid = one round).
// lds: A0[4096] B0[4096] A1[4096] B1[4096] bf16. 128x128 tile, 4 waves.
// ---------------------------------------------------------------------------
__device__ __forceinline__ void qkv_stage(
    const __hip_bfloat16* __restrict__ X, const __hip_bfloat16* __restrict__ W,
    __hip_bfloat16* A, __hip_bfloat16* B, int m0, int n0, int k0,
    int w, int lane) {
  for (int r = 0; r < 2; ++r) {
    int cbase = r * 256 + w * 64;
    int s = cbase + lane, row = s >> 2, cs = s & 3;
    int off = cs ^ ((row >> 1) & 3);
    async_load16((const char*)(X + (size_t)(m0 + row) * DIM + k0) + off * 16,
                 (char*)A + cbase * 16);
    async_load16((const char*)(W + (size_t)(n0 + row) * DIM + k0) + off * 16,
                 (char*)B + cbase * 16);
  }
}

__device__ __forceinline__ void gemm_mainloop_qkv(
    const __hip_bfloat16* __restrict__ X, const __hip_bfloat16* __restrict__ W,
    __hip_bfloat16* lds, int m0, int n0, f32x4 acc[4][4]) {
  const int tid = threadIdx.x, lane = tid & 63, w = tid >> 6;
  const int quad = lane >> 4, l15 = lane & 15;
  const int wm = (w >> 1) * 64, wn = (w & 1) * 64;

  f32x4 z = {0.f, 0.f, 0.f, 0.f};
  for (int mi = 0; mi < 4; ++mi)
    for (int ni = 0; ni < 4; ++ni) acc[mi][ni] = z;

  qkv_stage(X, W, lds, lds + 4096, m0, n0, 0, w, lane);
  __syncthreads();

  for (int it = 0; it < 32; ++it) {
    __hip_bfloat16* Ac = lds + (it & 1) * 8192;
    __hip_bfloat16* Bc = Ac + 4096;
    if (it < 31) {
      __hip_bfloat16* An = lds + ((it + 1) & 1) * 8192;
      qkv_stage(X, W, An, An + 4096, m0, n0, (it + 1) * 32, w, lane);
    }
    bf16x8 a[4], b[4];
    for (int mi = 0; mi < 4; ++mi)
      a[mi] = *(const bf16x8*)(Ac + swz32(wm + mi * 16 + l15, quad) * 8);
    for (int ni = 0; ni < 4; ++ni)
      b[ni] = *(const bf16x8*)(Bc + swz32(wn + ni * 16 + l15, quad) * 8);
    for (int mi = 0; mi < 4; ++mi)
      for (int ni = 0; ni < 4; ++ni)
        acc[mi][ni] = mfma16(a[mi], b[ni], acc[mi][ni]);
    __syncthreads();  // prefetch complete + all waves done with Ac/Bc
  }
}

// ---------------------------------------------------------------------------
// QKV projection. grid (8, 32, 3); 34.8 KB LDS -> 3 blocks/CU. q scaled by
// QSCALE, (B,H,S,dk); k (B,H,S,dk); v transposed (B,H,dk,S).
// ---------------------------------------------------------------------------
__global__ __launch_bounds__(256) void qkv_proj_kernel(
    const __hip_bfloat16* __restrict__ xq, const __hip_bfloat16* __restrict__ xk,
    const __hip_bfloat16* __restrict__ xv,
    const __hip_bfloat16* __restrict__ wq, const __hip_bfloat16* __restrict__ wk,
    const __hip_bfloat16* __restrict__ wv,
    const float* __restrict__ bq, const float* __restrict__ bk,
    const float* __restrict__ bv,
    __hip_bfloat16* __restrict__ q_ws, __hip_bfloat16* __restrict__ k_ws,
    __hip_bfloat16* __restrict__ vt_ws) {
  __shared__ __align__(16) __hip_bfloat16 S_lds[128 * ESTR];  // 34816 B

  const int z = blockIdx.z;
  const __hip_bfloat16* X = (z == 0) ? xq : ((z == 1) ? xk : xv);
  const __hip_bfloat16* W = (z == 0) ? wq : ((z == 1) ? wk : wv);
  const float* bias = (z == 0) ? bq : ((z == 1) ? bk : bv);
  const float f = (z == 0) ? QSCALE : 1.0f;

  const int m0 = blockIdx.y * 128, n0 = blockIdx.x * 128;
  f32x4 acc[4][4];
  gemm_mainloop_qkv(X, W, S_lds, m0, n0, acc);

  const int tid = threadIdx.x, lane = tid & 63, w = tid >> 6;
  const int quad = lane >> 4, l15 = lane & 15;
  const int wm = (w >> 1) * 64, wn = (w & 1) * 64;

  if (z != 2) {
    __hip_bfloat16* out = (z == 0) ? q_ws : k_ws;
    for (int mi = 0; mi < 4; ++mi)
      for (int ni = 0; ni < 4; ++ni) {
        const float bv_ = bias[n0 + wn + ni * 16 + l15];
        for (int r = 0; r < 4; ++r)
          S_lds[(wm + mi * 16 + quad * 4 + r) * ESTR + wn + ni * 16 + l15] =
              __float2bfloat16((acc[mi][ni][r] + bv_) * f);
      }
    __syncthreads();
    for (int r2 = 0; r2 < 8; ++r2) {
      int c = r2 * 256 + tid;
      int row = c >> 4, j = c & 15;
      int m = m0 + row, b = m >> 11, s = m & 2047;
      int n = n0 + j * 8, h = n >> 6, d = n & 63;
      *(uint4*)(out + ((size_t)(b * NH + h) * SEQ + s) * DK + d) =
          *(const uint4*)(S_lds + row * ESTR + j * 8);
    }
  } else {
    for (int mi = 0; mi < 4; ++mi)
      for (int ni = 0; ni < 4; ++ni) {
        const int n_local = wn + ni * 16 + l15;
        const float bv_ = bias[n0 + n_local];
        bf16x4 tv;
        for (int r = 0; r < 4; ++r) tv[r] = (__bf16)(acc[mi][ni][r] + bv_);
        *(bf16x4*)(S_lds + n_local * ESTR + wm + mi * 16 + quad * 4) = tv;
      }
    __syncthreads();
    const int b = m0 >> 11, s_base = m0 & 2047;
    for (int r2 = 0; r2 < 8; ++r2) {
      int c2 = r2 * 256 + tid;
      int nrow = c2 >> 4, moff = (c2 & 15) * 8;
      int n = n0 + nrow, h = n >> 6, d = n & 63;
      *(uint4*)(vt_ws + ((size_t)(b * NH + h) * DK + d) * SEQ + s_base + moff) =
          *(const uint4*)(S_lds + nrow * ESTR + moff);
    }
  }
}

// ---------------------------------------------------------------------------
// Flash attention (R12 k-split, frozen at 57.7 us). grid (16, 32) x 512.
// ---------------------------------------------------------------------------
__global__ __launch_bounds__(512, 4) void attn_kernel(
    const __hip_bfloat16* __restrict__ qg, const __hip_bfloat16* __restrict__ kg,
    const __hip_bfloat16* __restrict__ vtg, const int* __restrict__ mask,
    const float* __restrict__ biasg, __hip_bfloat16* __restrict__ ctx) {
  __shared__ __align__(16) char KV_raw[32768];   // K[2]/V[2] tiles; later fp32 scratch
  __shared__ __align__(16) __hip_bfloat16 P_lds[256 * PSTR];  // per-wave P
  __shared__ float osum_lds[4][32];

  __hip_bfloat16* K_lds = (__hip_bfloat16*)KV_raw;            // [2][4096]
  __hip_bfloat16* V_lds = (__hip_bfloat16*)(KV_raw + 16384);  // [2][4096]

  const int tid = threadIdx.x, lane = tid & 63, w = tid >> 6;
  const int quad = lane >> 4, l15 = lane & 15;
  const int g = w >> 1, half = w & 1;
  const int bh = blockIdx.y, b = bh >> 4, h = bh & 15;
  const int q0 = blockIdx.x * 128;
  const size_t head = (size_t)bh * SEQ * DK;
  const size_t vthead = (size_t)bh * DK * SEQ;

  bf16x8 qf[2][2];  // [kk][ni]
  for (int kk = 0; kk < 2; ++kk)
    for (int ni = 0; ni < 2; ++ni)
      qf[kk][ni] = *(const bf16x8*)(qg + head +
          (size_t)(q0 + g * 32 + ni * 16 + l15) * DK + kk * 32 + quad * 8);
  int qmv[2];
  for (int ni = 0; ni < 2; ++ni)
    qmv[ni] = mask[b * SEQ + q0 + g * 32 + ni * 16 + l15];
  const float* bias_b = biasg + b * SEQ;

  const bf16x8 ones = {(__bf16)1.f, (__bf16)1.f, (__bf16)1.f, (__bf16)1.f,
                       (__bf16)1.f, (__bf16)1.f, (__bf16)1.f, (__bf16)1.f};
  f32x4 z = {0.f, 0.f, 0.f, 0.f};
  f32x4 o_acc[2][4];
  for (int ni = 0; ni < 2; ++ni)
    for (int di = 0; di < 4; ++di) o_acc[ni][di] = z;
  f32x4 o_sum[2] = {z, z};
  __hip_bfloat16* P_w = P_lds + w * 32 * PSTR;

  for (int u = 0; u < 16; ++u) {
    {
      int row = tid >> 3, cs = tid & 7;
      int off = cs ^ (row & 7);
      async_load16((const char*)(kg + head + (size_t)(u * 64 + row) * DK) + off * 16,
                   (char*)K_lds + tid * 16);
      async_load16((const char*)(kg + head + (size_t)((16 + u) * 64 + row) * DK) + off * 16,
                   (char*)(K_lds + 4096) + tid * 16);
      async_load16((const char*)(vtg + vthead + (size_t)row * SEQ + u * 64) + off * 16,
                   (char*)V_lds + tid * 16);
      async_load16((const char*)(vtg + vthead + (size_t)row * SEQ + (16 + u) * 64) + off * 16,
                   (char*)(V_lds + 4096) + tid * 16);
    }
    __syncthreads();

    const __hip_bfloat16* Kc = K_lds + half * 4096;
    const __hip_bfloat16* Vc = V_lds + half * 4096;
    const int kbase = (half * 16 + u) * 64;

    f32x4 s_acc[4][2];
    for (int mi = 0; mi < 4; ++mi) {
      f32x4 kb = *(const f32x4*)(bias_b + kbase + mi * 16 + quad * 4);
      for (int ni = 0; ni < 2; ++ni) s_acc[mi][ni] = kb;
    }
    for (int kk = 0; kk < 2; ++kk) {
      bf16x8 ak[4];
      for (int mi = 0; mi < 4; ++mi)
        ak[mi] = *(const bf16x8*)(Kc + swz(mi * 16 + l15, kk * 4 + quad) * 8);
      for (int mi = 0; mi < 4; ++mi)
        for (int ni = 0; ni < 2; ++ni)
          s_acc[mi][ni] = mfma16(ak[mi], qf[kk][ni], s_acc[mi][ni]);
    }

    for (int mi = 0; mi < 4; ++mi)
      for (int ni = 0; ni < 2; ++ni) {
        bf16x4 pk;
        for (int r = 0; r < 4; ++r) {
          float s2 = qmv[ni] ? s_acc[mi][ni][r] : 0.f;
          pk[r] = (__bf16)__builtin_amdgcn_exp2f(s2);
        }
        *(bf16x4*)(P_w + (ni * 16 + l15) * PSTR + mi * 16 + quad * 4) = pk;
      }

    for (int kk = 0; kk < 2; ++kk) {
      bf16x8 av[4], bp[2];
      for (int di = 0; di < 4; ++di)
        av[di] = *(const bf16x8*)(Vc + swz(di * 16 + l15, kk * 4 + quad) * 8);
      for (int ni = 0; ni < 2; ++ni)
        bp[ni] = *(const bf16x8*)(P_w + (ni * 16 + l15) * PSTR + kk * 32 + quad * 8);
      for (int ni = 0; ni < 2; ++ni) {
        for (int di = 0; di < 4; ++di)
          o_acc[ni][di] = mfma16(av[di], bp[ni], o_acc[ni][di]);
        o_sum[ni] = mfma16(ones, bp[ni], o_sum[ni]);
      }
    }
    __syncthreads();
  }

  // combine halves (additive; exact)
  float* scr = (float*)KV_raw;
  if (half == 0) {
    for (int ni = 0; ni < 2; ++ni)
      for (int di = 0; di < 4; ++di) {
        int row = g * 32 + ni * 16 + l15, ch = di * 4 + quad;
        *(f32x4*)(scr + (row * 16 + (ch ^ (row & 7))) * 4) = o_acc[ni][di];
      }
    if (quad == 0)
      for (int ni = 0; ni < 2; ++ni)
        osum_lds[g][ni * 16 + l15] = o_sum[ni][0];
  }
  __syncthreads();
  if (half == 1) {
    float inv[2];
    for (int ni = 0; ni < 2; ++ni)
      inv[ni] = 1.f / (o_sum[ni][0] + osum_lds[g][ni * 16 + l15]);
    for (int ni = 0; ni < 2; ++ni)
      for (int di = 0; di < 4; ++di) {
        int row = g * 32 + ni * 16 + l15, ch = di * 4 + quad;
        f32x4 part = *(const f32x4*)(scr + (row * 16 + (ch ^ (row & 7))) * 4);
        bf16x4 ov;
        for (int r = 0; r < 4; ++r)
          ov[r] = (__bf16)((o_acc[ni][di][r] + part[r]) * inv[ni]);
        *(bf16x4*)(P_lds + row * PSTR + di * 16 + quad * 4) = ov;
      }
  }
  __syncthreads();
  for (int r = 0; r < 2; ++r) {
    int c = r * 512 + tid, row = c >> 3, off = c & 7;
    *(uint4*)(ctx + (size_t)(b * SEQ + q0 + row) * DIM + h * DK + off * 8) =
        *(const uint4*)(P_lds + row * PSTR + off * 8);
  }
}

// ---------------------------------------------------------------------------
// Output projection: 64x128 tiles -> grid (8, 64) = 512 blocks = 2/CU.
// BK=32 double-buffered (24 KB staging, unioned with 33.8 KB fp32 epilogue).
// 4 waves: wm=(w>>1)*32 (2 row halves), wn=(w&1)*64; acc[2][4].
// ---------------------------------------------------------------------------
__global__ __launch_bounds__(256) void out_proj_kernel(
    const __hip_bfloat16* __restrict__ ctx, const __hip_bfloat16* __restrict__ wo,
    const float* __restrict__ bo, float* __restrict__ out) {
  __shared__ __align__(16) char S_raw[64 * FSTR * 4];  // 33792 B
  __hip_bfloat16* lds = (__hip_bfloat16*)S_raw;

  const int tid = threadIdx.x, lane = tid & 63, w = tid >> 6;
  const int quad = lane >> 4, l15 = lane & 15;
  const int wm = (w >> 1) * 32, wn = (w & 1) * 64;
  const int m0 = blockIdx.y * 64, n0 = blockIdx.x * 128;

  f32x4 z = {0.f, 0.f, 0.f, 0.f};
  f32x4 acc[2][4];
  for (int mi = 0; mi < 2; ++mi)
    for (int ni = 0; ni < 4; ++ni) acc[mi][ni] = z;

  // stage buf k: A (64x32, 2048 elems) at k*6144, B (128x32, 4096) at +2048
  auto stage = [&](int buf, int k0) {
    __hip_bfloat16* A = lds + buf * 6144;
    __hip_bfloat16* B = A + 2048;
    {  // A: 256 chunks, 1/thread
      int cbase = w * 64;
      int s = cbase + lane, row = s >> 2, cs = s & 3;
      int off = cs ^ ((row >> 1) & 3);
      async_load16((const char*)(ctx + (size_t)(m0 + row) * DIM + k0) + off * 16,
                   (char*)A + cbase * 16);
    }
    for (int r = 0; r < 2; ++r) {  // B: 512 chunks, 2/thread
      int cbase = r * 256 + w * 64;
      int s = cbase + lane, row = s >> 2, cs = s & 3;
      int off = cs ^ ((row >> 1) & 3);
      async_load16((const char*)(wo + (size_t)(n0 + row) * DIM + k0) + off * 16,
                   (char*)B + cbase * 16);
    }
  };

  stage(0, 0);
  __syncthreads();
  for (int it = 0; it < 32; ++it) {
    __hip_bfloat16* Ac = lds + (it & 1) * 6144;
    __hip_bfloat16* Bc = Ac + 2048;
    if (it < 31) stage((it + 1) & 1, (it + 1) * 32);
    bf16x8 a[2], b[4];
    for (int mi = 0; mi < 2; ++mi)
      a[mi] = *(const bf16x8*)(Ac + swz32(wm + mi * 16 + l15, quad) * 8);
    for (int ni = 0; ni < 4; ++ni)
      b[ni] = *(const bf16x8*)(Bc + swz32(wn + ni * 16 + l15, quad) * 8);
    for (int mi = 0; mi < 2; ++mi)
      for (int ni = 0; ni < 4; ++ni)
        acc[mi][ni] = mfma16(a[mi], b[ni], acc[mi][ni]);
    __syncthreads();
  }

  float* epi = (float*)S_raw;
  for (int mi = 0; mi < 2; ++mi)
    for (int ni = 0; ni < 4; ++ni) {
      const float bv_ = bo[n0 + wn + ni * 16 + l15];
      for (int r = 0; r < 4; ++r)
        epi[(wm + mi * 16 + quad * 4 + r) * FSTR + wn + ni * 16 + l15] =
            acc[mi][ni][r] + bv_;
    }
  __syncthreads();
  for (int r2 = 0; r2 < 8; ++r2) {
    int c = r2 * 256 + tid;
    int row = c >> 5, j = c & 31;
    *(float4*)(out + (size_t)(m0 + row) * DIM + n0 + j * 4) =
        *(const float4*)(epi + row * FSTR + j * 4);
  }
}

extern "C" void kernel_launch(void* const* d_in, const int* in_sizes, int n_in,
                              void* d_out, int out_size, void* d_ws, size_t ws_size,
                              hipStream_t stream) {
  const float* query = (const float*)d_in[0];
  const float* key   = (const float*)d_in[1];
  const float* value = (const float*)d_in[2];
  const int*   mask  = (const int*)d_in[3];
  const float* wq = (const float*)d_in[4];
  const float* bq = (const float*)d_in[5];
  const float* wk = (const float*)d_in[6];
  const float* bk = (const float*)d_in[7];
  const float* wv = (const float*)d_in[8];
  const float* bv = (const float*)d_in[9];
  const float* wo = (const float*)d_in[10];
  const float* bo = (const float*)d_in[11];
  float* out = (float*)d_out;

  char* ws = (char*)d_ws;
  const size_t SZA = (size_t)NA * 2;  // 8 MiB bf16 activation
  const size_t SZW = (size_t)NW * 2;  // 2 MiB bf16 weight
  __hip_bfloat16* xq  = (__hip_bfloat16*)(ws);
  __hip_bfloat16* xk  = (__hip_bfloat16*)(ws + SZA);
  __hip_bfloat16* xv  = (__hip_bfloat16*)(ws + 2 * SZA);
  __hip_bfloat16* wqb = (__hip_bfloat16*)(ws + 3 * SZA);
  __hip_bfloat16* wkb = (__hip_bfloat16*)(ws + 3 * SZA + SZW);
  __hip_bfloat16* wvb = (__hip_bfloat16*)(ws + 3 * SZA + 2 * SZW);
  __hip_bfloat16* wob = (__hip_bfloat16*)(ws + 3 * SZA + 3 * SZW);
  __hip_bfloat16* q_ws  = (__hip_bfloat16*)(ws + 3 * SZA + 4 * SZW);
  __hip_bfloat16* k_ws  = (__hip_bfloat16*)(ws + 4 * SZA + 4 * SZW);
  __hip_bfloat16* vt_ws = (__hip_bfloat16*)(ws + 5 * SZA + 4 * SZW);
  float* biasg = (float*)(ws + 6 * SZA + 4 * SZW);  // 16 KB
  __hip_bfloat16* ctx_ws = xq;  // xq dead after qkv_proj

  cvt_kernel<<<dim3(8193), dim3(256), 0, stream>>>(
      query, key, value, wq, wk, wv, wo, mask,
      xq, xk, xv, wqb, wkb, wvb, wob, biasg);
  qkv_proj_kernel<<<dim3(8, 32, 3), dim3(256), 0, stream>>>(
      xq, xk, xv, wqb, wkb, wvb, bq, bk, bv, q_ws, k_ws, vt_ws);
  attn_kernel<<<dim3(16, 32), dim3(512), 0, stream>>>(
      q_ws, k_ws, vt_ws, mask, biasg, ctx_ws);
  out_proj_kernel<<<dim3(8, 64), dim3(256), 0, stream>>>(ctx_ws, wob, bo, out);
}

// Round 14
// 219.613 us; speedup vs baseline: 1.0250x; 1.0250x over previous
//
#include <hip/hip_runtime.h>
#include <hip/hip_bf16.h>

// B=2, S=2048, D=1024, H=16, dk=64. fp32 in/out; bf16 MFMA compute.
#define SEQ 2048
#define DIM 1024
#define NH  16
#define DK  64
#define NA  (2 * SEQ * DIM)   // activation elems
#define NW  (DIM * DIM)       // weight elems
#define PSTR 72               // padded P row stride (bf16)
#define ESTR 136              // epilogue bf16 tile stride (16B-aligned rows)
#define FSTR 132              // epilogue fp32 tile stride (16B-aligned rows)
#define QSCALE 0.18033688011112042f  // 0.125 * log2(e)

typedef __attribute__((ext_vector_type(4))) float f32x4;
typedef __attribute__((ext_vector_type(8))) __bf16 bf16x8;
typedef __attribute__((ext_vector_type(4))) __bf16 bf16x4;

__device__ __forceinline__ f32x4 mfma16(bf16x8 a, bf16x8 b, f32x4 c) {
  return __builtin_amdgcn_mfma_f32_16x16x32_bf16(a, b, c, 0, 0, 0);
}
__device__ __forceinline__ void async_load16(const void* g, void* l) {
  __builtin_amdgcn_global_load_lds(
      (const __attribute__((address_space(1))) void*)g,
      (__attribute__((address_space(3))) void*)l, 16, 0, 0);
}
// XOR-swizzled 16B-chunk slot for a [rows x 64bf16] tile.
__device__ __forceinline__ int swz(int row, int chunk) {
  return row * 8 + (chunk ^ (row & 7));
}

// ---------------------------------------------------------------------------
// fp32 -> bf16 conversion + mask->bias precompute. grid 8193.
// ---------------------------------------------------------------------------
__global__ __launch_bounds__(256) void cvt_kernel(
    const float* __restrict__ s0, const float* __restrict__ s1,
    const float* __restrict__ s2, const float* __restrict__ s3,
    const float* __restrict__ s4, const float* __restrict__ s5,
    const float* __restrict__ s6, const int* __restrict__ mask,
    __hip_bfloat16* __restrict__ d0, __hip_bfloat16* __restrict__ d1,
    __hip_bfloat16* __restrict__ d2, __hip_bfloat16* __restrict__ d3,
    __hip_bfloat16* __restrict__ d4, __hip_bfloat16* __restrict__ d5,
    __hip_bfloat16* __restrict__ d6, float* __restrict__ biasg) {
  const int id = blockIdx.x;
  if (id == 8192) {
    for (int i = threadIdx.x; i < 2 * SEQ; i += 256)
      biasg[i] = mask[i] ? 0.f : -1e9f;
    return;
  }
  const float* s;
  __hip_bfloat16* d;
  int bid;
  if (id < 6144) {
    int t = id >> 11;
    bid = id & 2047;
    s = (t == 0) ? s0 : ((t == 1) ? s1 : s2);
    d = (t == 0) ? d0 : ((t == 1) ? d1 : d2);
  } else {
    int t = (id - 6144) >> 9;
    bid = (id - 6144) & 511;
    s = (t == 0) ? s3 : ((t == 1) ? s4 : ((t == 2) ? s5 : s6));
    d = (t == 0) ? d3 : ((t == 1) ? d4 : ((t == 2) ? d5 : d6));
  }
  size_t i = ((size_t)bid * 256 + threadIdx.x) * 8;
  float4 a = *(const float4*)(s + i);
  float4 b = *(const float4*)(s + i + 4);
  bf16x8 v = {(__bf16)a.x, (__bf16)a.y, (__bf16)a.z, (__bf16)a.w,
              (__bf16)b.x, (__bf16)b.y, (__bf16)b.z, (__bf16)b.w};
  *(bf16x8*)(d + i) = v;
}

// ---------------------------------------------------------------------------
// Double-buffered async NT-GEMM mainloop, ONE barrier/iter (R9/R12 version).
// lds: A0[8192] B0[8192] A1[8192] B1[8192] bf16 (64 KB). 128x128 tile.
// ---------------------------------------------------------------------------
__device__ __forceinline__ void gemm_stage(
    const __hip_bfloat16* __restrict__ X, const __hip_bfloat16* __restrict__ W,
    __hip_bfloat16* A, __hip_bfloat16* B, int m0, int n0, int k0,
    int w, int lane) {
  for (int r = 0; r < 4; ++r) {
    int cbase = r * 256 + w * 64;
    int c = cbase + lane, row = c >> 3, cs = c & 7;
    int off = cs ^ (row & 7);
    async_load16((const char*)(X + (size_t)(m0 + row) * DIM + k0) + off * 16,
                 (char*)A + cbase * 16);
    async_load16((const char*)(W + (size_t)(n0 + row) * DIM + k0) + off * 16,
                 (char*)B + cbase * 16);
  }
}

__device__ __forceinline__ void gemm_mainloop(
    const __hip_bfloat16* __restrict__ X, const __hip_bfloat16* __restrict__ W,
    __hip_bfloat16* lds, int m0, int n0, f32x4 acc[4][4]) {
  const int tid = threadIdx.x, lane = tid & 63, w = tid >> 6;
  const int quad = lane >> 4, l15 = lane & 15;
  const int wm = (w >> 1) * 64, wn = (w & 1) * 64;

  f32x4 z = {0.f, 0.f, 0.f, 0.f};
  for (int mi = 0; mi < 4; ++mi)
    for (int ni = 0; ni < 4; ++ni) acc[mi][ni] = z;

  gemm_stage(X, W, lds, lds + 8192, m0, n0, 0, w, lane);
  __syncthreads();

  for (int it = 0; it < 16; ++it) {
    __hip_bfloat16* Ac = lds + (it & 1) * 16384;
    __hip_bfloat16* Bc = Ac + 8192;
    if (it < 15) {
      __hip_bfloat16* An = lds + ((it + 1) & 1) * 16384;
      gemm_stage(X, W, An, An + 8192, m0, n0, (it + 1) * 64, w, lane);
    }
    for (int kk = 0; kk < 2; ++kk) {
      bf16x8 a[4], b[4];
      for (int mi = 0; mi < 4; ++mi)
        a[mi] = *(const bf16x8*)(Ac + swz(wm + mi * 16 + l15, kk * 4 + quad) * 8);
      for (int ni = 0; ni < 4; ++ni)
        b[ni] = *(const bf16x8*)(Bc + swz(wn + ni * 16 + l15, kk * 4 + quad) * 8);
      for (int mi = 0; mi < 4; ++mi)
        for (int ni = 0; ni < 4; ++ni)
          acc[mi][ni] = mfma16(a[mi], b[ni], acc[mi][ni]);
    }
    __syncthreads();
  }
}

// ---------------------------------------------------------------------------
// QKV projection (R12 version). grid (8, 32, 3). q scaled by QSCALE,
// (B,H,S,dk); k (B,H,S,dk); v transposed (B,H,dk,S).
// ---------------------------------------------------------------------------
__global__ __launch_bounds__(256) void qkv_proj_kernel(
    const __hip_bfloat16* __restrict__ xq, const __hip_bfloat16* __restrict__ xk,
    const __hip_bfloat16* __restrict__ xv,
    const __hip_bfloat16* __restrict__ wq, const __hip_bfloat16* __restrict__ wk,
    const __hip_bfloat16* __restrict__ wv,
    const float* __restrict__ bq, const float* __restrict__ bk,
    const float* __restrict__ bv,
    __hip_bfloat16* __restrict__ q_ws, __hip_bfloat16* __restrict__ k_ws,
    __hip_bfloat16* __restrict__ vt_ws) {
  __shared__ __align__(16) __hip_bfloat16 S_lds[4 * 8192];  // 65536 B

  const int z = blockIdx.z;
  const __hip_bfloat16* X = (z == 0) ? xq : ((z == 1) ? xk : xv);
  const __hip_bfloat16* W = (z == 0) ? wq : ((z == 1) ? wk : wv);
  const float* bias = (z == 0) ? bq : ((z == 1) ? bk : bv);
  const float f = (z == 0) ? QSCALE : 1.0f;

  const int m0 = blockIdx.y * 128, n0 = blockIdx.x * 128;
  f32x4 acc[4][4];
  gemm_mainloop(X, W, S_lds, m0, n0, acc);

  const int tid = threadIdx.x, lane = tid & 63, w = tid >> 6;
  const int quad = lane >> 4, l15 = lane & 15;
  const int wm = (w >> 1) * 64, wn = (w & 1) * 64;

  if (z != 2) {
    __hip_bfloat16* out = (z == 0) ? q_ws : k_ws;
    for (int mi = 0; mi < 4; ++mi)
      for (int ni = 0; ni < 4; ++ni) {
        const float bv_ = bias[n0 + wn + ni * 16 + l15];
        for (int r = 0; r < 4; ++r)
          S_lds[(wm + mi * 16 + quad * 4 + r) * ESTR + wn + ni * 16 + l15] =
              __float2bfloat16((acc[mi][ni][r] + bv_) * f);
      }
    __syncthreads();
    for (int r2 = 0; r2 < 8; ++r2) {
      int c = r2 * 256 + tid;
      int row = c >> 4, j = c & 15;
      int m = m0 + row, b = m >> 11, s = m & 2047;
      int n = n0 + j * 8, h = n >> 6, d = n & 63;
      *(uint4*)(out + ((size_t)(b * NH + h) * SEQ + s) * DK + d) =
          *(const uint4*)(S_lds + row * ESTR + j * 8);
    }
  } else {
    for (int mi = 0; mi < 4; ++mi)
      for (int ni = 0; ni < 4; ++ni) {
        const int n_local = wn + ni * 16 + l15;
        const float bv_ = bias[n0 + n_local];
        bf16x4 tv;
        for (int r = 0; r < 4; ++r) tv[r] = (__bf16)(acc[mi][ni][r] + bv_);
        *(bf16x4*)(S_lds + n_local * ESTR + wm + mi * 16 + quad * 4) = tv;
      }
    __syncthreads();
    const int b = m0 >> 11, s_base = m0 & 2047;
    for (int r2 = 0; r2 < 8; ++r2) {
      int c2 = r2 * 256 + tid;
      int nrow = c2 >> 4, moff = (c2 & 15) * 8;
      int n = n0 + nrow, h = n >> 6, d = n & 63;
      *(uint4*)(vt_ws + ((size_t)(b * NH + h) * DK + d) * SEQ + s_base + moff) =
          *(const uint4*)(S_lds + nrow * ESTR + moff);
    }
  }
}

// ---------------------------------------------------------------------------
// Flash attention (R12 k-split) + XCD-aware HEAD-MAJOR block swizzle:
// gid = y*16+x; bh = gid & 31; q-tile = gid >> 5. All 16 blocks of a head
// share gid mod 32 == bh -> same residue mod 8 -> same XCD under round-robin
// dispatch -> each head's K/V is fetched into exactly ONE per-XCD L2
// (predict FETCH_SIZE 70 -> ~28 MB). Heuristic only; correctness unaffected.
// ---------------------------------------------------------------------------
__global__ __launch_bounds__(512, 4) void attn_kernel(
    const __hip_bfloat16* __restrict__ qg, const __hip_bfloat16* __restrict__ kg,
    const __hip_bfloat16* __restrict__ vtg, const int* __restrict__ mask,
    const float* __restrict__ biasg, __hip_bfloat16* __restrict__ ctx) {
  __shared__ __align__(16) char KV_raw[32768];   // K[2]/V[2] tiles; later fp32 scratch
  __shared__ __align__(16) __hip_bfloat16 P_lds[256 * PSTR];  // per-wave P
  __shared__ float osum_lds[4][32];

  __hip_bfloat16* K_lds = (__hip_bfloat16*)KV_raw;            // [2][4096]
  __hip_bfloat16* V_lds = (__hip_bfloat16*)(KV_raw + 16384);  // [2][4096]

  const int tid = threadIdx.x, lane = tid & 63, w = tid >> 6;
  const int quad = lane >> 4, l15 = lane & 15;
  const int g = w >> 1, half = w & 1;
  const int gid = blockIdx.y * 16 + blockIdx.x;   // linear dispatch id
  const int bh = gid & 31, b = bh >> 4, h = bh & 15;
  const int q0 = (gid >> 5) * 128;
  const size_t head = (size_t)bh * SEQ * DK;
  const size_t vthead = (size_t)bh * DK * SEQ;

  bf16x8 qf[2][2];  // [kk][ni]
  for (int kk = 0; kk < 2; ++kk)
    for (int ni = 0; ni < 2; ++ni)
      qf[kk][ni] = *(const bf16x8*)(qg + head +
          (size_t)(q0 + g * 32 + ni * 16 + l15) * DK + kk * 32 + quad * 8);
  int qmv[2];
  for (int ni = 0; ni < 2; ++ni)
    qmv[ni] = mask[b * SEQ + q0 + g * 32 + ni * 16 + l15];
  const float* bias_b = biasg + b * SEQ;

  const bf16x8 ones = {(__bf16)1.f, (__bf16)1.f, (__bf16)1.f, (__bf16)1.f,
                       (__bf16)1.f, (__bf16)1.f, (__bf16)1.f, (__bf16)1.f};
  f32x4 z = {0.f, 0.f, 0.f, 0.f};
  f32x4 o_acc[2][4];
  for (int ni = 0; ni < 2; ++ni)
    for (int di = 0; di < 4; ++di) o_acc[ni][di] = z;
  f32x4 o_sum[2] = {z, z};
  __hip_bfloat16* P_w = P_lds + w * 32 * PSTR;

  for (int u = 0; u < 16; ++u) {
    {
      int row = tid >> 3, cs = tid & 7;
      int off = cs ^ (row & 7);
      async_load16((const char*)(kg + head + (size_t)(u * 64 + row) * DK) + off * 16,
                   (char*)K_lds + tid * 16);
      async_load16((const char*)(kg + head + (size_t)((16 + u) * 64 + row) * DK) + off * 16,
                   (char*)(K_lds + 4096) + tid * 16);
      async_load16((const char*)(vtg + vthead + (size_t)row * SEQ + u * 64) + off * 16,
                   (char*)V_lds + tid * 16);
      async_load16((const char*)(vtg + vthead + (size_t)row * SEQ + (16 + u) * 64) + off * 16,
                   (char*)(V_lds + 4096) + tid * 16);
    }
    __syncthreads();

    const __hip_bfloat16* Kc = K_lds + half * 4096;
    const __hip_bfloat16* Vc = V_lds + half * 4096;
    const int kbase = (half * 16 + u) * 64;

    f32x4 s_acc[4][2];
    for (int mi = 0; mi < 4; ++mi) {
      f32x4 kb = *(const f32x4*)(bias_b + kbase + mi * 16 + quad * 4);
      for (int ni = 0; ni < 2; ++ni) s_acc[mi][ni] = kb;
    }
    for (int kk = 0; kk < 2; ++kk) {
      bf16x8 ak[4];
      for (int mi = 0; mi < 4; ++mi)
        ak[mi] = *(const bf16x8*)(Kc + swz(mi * 16 + l15, kk * 4 + quad) * 8);
      for (int mi = 0; mi < 4; ++mi)
        for (int ni = 0; ni < 2; ++ni)
          s_acc[mi][ni] = mfma16(ak[mi], qf[kk][ni], s_acc[mi][ni]);
    }

    for (int mi = 0; mi < 4; ++mi)
      for (int ni = 0; ni < 2; ++ni) {
        bf16x4 pk;
        for (int r = 0; r < 4; ++r) {
          float s2 = qmv[ni] ? s_acc[mi][ni][r] : 0.f;
          pk[r] = (__bf16)__builtin_amdgcn_exp2f(s2);
        }
        *(bf16x4*)(P_w + (ni * 16 + l15) * PSTR + mi * 16 + quad * 4) = pk;
      }

    for (int kk = 0; kk < 2; ++kk) {
      bf16x8 av[4], bp[2];
      for (int di = 0; di < 4; ++di)
        av[di] = *(const bf16x8*)(Vc + swz(di * 16 + l15, kk * 4 + quad) * 8);
      for (int ni = 0; ni < 2; ++ni)
        bp[ni] = *(const bf16x8*)(P_w + (ni * 16 + l15) * PSTR + kk * 32 + quad * 8);
      for (int ni = 0; ni < 2; ++ni) {
        for (int di = 0; di < 4; ++di)
          o_acc[ni][di] = mfma16(av[di], bp[ni], o_acc[ni][di]);
        o_sum[ni] = mfma16(ones, bp[ni], o_sum[ni]);
      }
    }
    __syncthreads();
  }

  // combine halves (additive; exact)
  float* scr = (float*)KV_raw;
  if (half == 0) {
    for (int ni = 0; ni < 2; ++ni)
      for (int di = 0; di < 4; ++di) {
        int row = g * 32 + ni * 16 + l15, ch = di * 4 + quad;
        *(f32x4*)(scr + (row * 16 + (ch ^ (row & 7))) * 4) = o_acc[ni][di];
      }
    if (quad == 0)
      for (int ni = 0; ni < 2; ++ni)
        osum_lds[g][ni * 16 + l15] = o_sum[ni][0];
  }
  __syncthreads();
  if (half == 1) {
    float inv[2];
    for (int ni = 0; ni < 2; ++ni)
      inv[ni] = 1.f / (o_sum[ni][0] + osum_lds[g][ni * 16 + l15]);
    for (int ni = 0; ni < 2; ++ni)
      for (int di = 0; di < 4; ++di) {
        int row = g * 32 + ni * 16 + l15, ch = di * 4 + quad;
        f32x4 part = *(const f32x4*)(scr + (row * 16 + (ch ^ (row & 7))) * 4);
        bf16x4 ov;
        for (int r = 0; r < 4; ++r)
          ov[r] = (__bf16)((o_acc[ni][di][r] + part[r]) * inv[ni]);
        *(bf16x4*)(P_lds + row * PSTR + di * 16 + quad * 4) = ov;
      }
  }
  __syncthreads();
  for (int r = 0; r < 2; ++r) {
    int c = r * 512 + tid, row = c >> 3, off = c & 7;
    *(uint4*)(ctx + (size_t)(b * SEQ + q0 + row) * DIM + h * DK + off * 8) =
        *(const uint4*)(P_lds + row * PSTR + off * 8);
  }
}

// ---------------------------------------------------------------------------
// Output projection (R12 version): out = ctx @ wo^T + bo. grid (8,32).
// Single-pass LDS-coalesced fp32 epilogue.
// ---------------------------------------------------------------------------
__global__ __launch_bounds__(256) void out_proj_kernel(
    const __hip_bfloat16* __restrict__ ctx, const __hip_bfloat16* __restrict__ wo,
    const float* __restrict__ bo, float* __restrict__ out) {
  __shared__ __align__(16) char S_raw[128 * FSTR * 4];  // 67584 B (>= 65536)
  __hip_bfloat16* S_lds = (__hip_bfloat16*)S_raw;

  const int m0 = blockIdx.y * 128, n0 = blockIdx.x * 128;
  f32x4 acc[4][4];
  gemm_mainloop(ctx, wo, S_lds, m0, n0, acc);

  const int tid = threadIdx.x, lane = tid & 63, w = tid >> 6;
  const int quad = lane >> 4, l15 = lane & 15;
  const int wm = (w >> 1) * 64, wn = (w & 1) * 64;
  float* epi = (float*)S_raw;

  for (int mi = 0; mi < 4; ++mi)
    for (int ni = 0; ni < 4; ++ni) {
      const float bv_ = bo[n0 + wn + ni * 16 + l15];
      for (int r = 0; r < 4; ++r)
        epi[(wm + mi * 16 + quad * 4 + r) * FSTR + wn + ni * 16 + l15] =
            acc[mi][ni][r] + bv_;
    }
  __syncthreads();
  for (int r2 = 0; r2 < 16; ++r2) {
    int c = r2 * 256 + tid;
    int row = c >> 5, j = c & 31;
    *(float4*)(out + (size_t)(m0 + row) * DIM + n0 + j * 4) =
        *(const float4*)(epi + row * FSTR + j * 4);
  }
}

extern "C" void kernel_launch(void* const* d_in, const int* in_sizes, int n_in,
                              void* d_out, int out_size, void* d_ws, size_t ws_size,
                              hipStream_t stream) {
  const float* query = (const float*)d_in[0];
  const float* key   = (const float*)d_in[1];
  const float* value = (const float*)d_in[2];
  const int*   mask  = (const int*)d_in[3];
  const float* wq = (const float*)d_in[4];
  const float* bq = (const float*)d_in[5];
  const float* wk = (const float*)d_in[6];
  const float* bk = (const float*)d_in[7];
  const float* wv = (const float*)d_in[8];
  const float* bv = (const float*)d_in[9];
  const float* wo = (const float*)d_in[10];
  const float* bo = (const float*)d_in[11];
  float* out = (float*)d_out;

  char* ws = (char*)d_ws;
  const size_t SZA = (size_t)NA * 2;  // 8 MiB bf16 activation
  const size_t SZW = (size_t)NW * 2;  // 2 MiB bf16 weight
  __hip_bfloat16* xq  = (__hip_bfloat16*)(ws);
  __hip_bfloat16* xk  = (__hip_bfloat16*)(ws + SZA);
  __hip_bfloat16* xv  = (__hip_bfloat16*)(ws + 2 * SZA);
  __hip_bfloat16* wqb = (__hip_bfloat16*)(ws + 3 * SZA);
  __hip_bfloat16* wkb = (__hip_bfloat16*)(ws + 3 * SZA + SZW);
  __hip_bfloat16* wvb = (__hip_bfloat16*)(ws + 3 * SZA + 2 * SZW);
  __hip_bfloat16* wob = (__hip_bfloat16*)(ws + 3 * SZA + 3 * SZW);
  __hip_bfloat16* q_ws  = (__hip_bfloat16*)(ws + 3 * SZA + 4 * SZW);
  __hip_bfloat16* k_ws  = (__hip_bfloat16*)(ws + 4 * SZA + 4 * SZW);
  __hip_bfloat16* vt_ws = (__hip_bfloat16*)(ws + 5 * SZA + 4 * SZW);
  float* biasg = (float*)(ws + 6 * SZA + 4 * SZW);  // 16 KB
  __hip_bfloat16* ctx_ws = xq;  // xq dead after qkv_proj

  cvt_kernel<<<dim3(8193), dim3(256), 0, stream>>>(
      query, key, value, wq, wk, wv, wo, mask,
      xq, xk, xv, wqb, wkb, wvb, wob, biasg);
  qkv_proj_kernel<<<dim3(8, 32, 3), dim3(256), 0, stream>>>(
      xq, xk, xv, wqb, wkb, wvb, bq, bk, bv, q_ws, k_ws, vt_ws);
  attn_kernel<<<dim3(16, 32), dim3(512), 0, stream>>>(
      q_ws, k_ws, vt_ws, mask, biasg, ctx_ws);
  out_proj_kernel<<<dim3(8, 32), dim3(256), 0, stream>>>(ctx_ws, wob, bo, out);
}